// Round 3
// baseline (122.386 us; speedup 1.0000x reference)
//
#include <hip/hip_runtime.h>
#include <hip/hip_bf16.h>

#define NN 8192
#define F 64
#define ALPHA 0.2f
#define L2E 1.44269504f
#define DBOUND 16.0f

typedef __attribute__((ext_vector_type(8))) short short8;
typedef __attribute__((ext_vector_type(4))) float f32x4;

__device__ __forceinline__ unsigned fb(float x) {
    return __builtin_bit_cast(unsigned, x);
}
__device__ __forceinline__ short f2bf(float x) {
    union { float f; unsigned u; } v; v.f = x;
    unsigned r = v.u + 0x7FFF + ((v.u >> 16) & 1);
    return (short)(r >> 16);
}

// Kernel A: Wh = h @ W^T (fp32), store WhT (bf16, transposed 64 x 8192),
// src = Wh@a1 (raw), dst2 = (Wh@a2) * log2(e)  (prescaled for k_attn).
__global__ __launch_bounds__(256) void k_prep(const float* __restrict__ h,
        const float* __restrict__ W, const float* __restrict__ a,
        short* __restrict__ WhT, float* __restrict__ src, float* __restrict__ dst2) {
    __shared__ float Wl[F][F + 1];
    __shared__ short shT[F][4];
    int tid = threadIdx.x;
    for (int m = 0; m < 4; ++m) {
        int idx = m * 1024 + tid * 4;
        float4 v = *(const float4*)&W[idx];
        int row = idx >> 6, col = idx & 63;
        Wl[row][col] = v.x; Wl[row][col + 1] = v.y;
        Wl[row][col + 2] = v.z; Wl[row][col + 3] = v.w;
    }
    __syncthreads();
    int w = tid >> 6, lane = tid & 63;
    int i = blockIdx.x * 4 + w;
    const float* hrow = &h[(size_t)i * F];
    float wh = 0.f;
    #pragma unroll
    for (int k = 0; k < F; k += 4) {
        float4 hv = *(const float4*)&hrow[k];
        wh += hv.x * Wl[lane][k] + hv.y * Wl[lane][k + 1]
            + hv.z * Wl[lane][k + 2] + hv.w * Wl[lane][k + 3];
    }
    shT[lane][w] = f2bf(wh);
    float s1 = wh * a[lane];
    float s2 = wh * a[F + lane];
    #pragma unroll
    for (int off = 32; off; off >>= 1) {
        s1 += __shfl_xor(s1, off);
        s2 += __shfl_xor(s2, off);
    }
    if (lane == 0) { src[i] = s1; dst2[i] = s2 * L2E; }
    __syncthreads();
    if (tid < F) {
        short4 v = make_short4(shT[tid][0], shT[tid][1], shT[tid][2], shT[tid][3]);
        *(short4*)&WhT[(size_t)tid * NN + blockIdx.x * 4] = v;
    }
}

// Kernel B: fused masked-softmax attention. Shared UPPER-BOUND max (srcv+DBOUND)
// -> no cross-row reduction needed; over-estimate cancels in normalization.
// All three streams (adj, dst2, WhT) depth-1 register double-buffered so the
// pre-compute wait is vmcnt(8), never vmcnt(0).
__global__ __launch_bounds__(256, 4) void k_attn(const int* __restrict__ adj,
        const short* __restrict__ WhT, const float* __restrict__ src,
        const float* __restrict__ dst2,
        float* __restrict__ Opart, float* __restrict__ lpart, int G) {
    int rb = blockIdx.x / G;
    int g  = blockIdx.x % G;
    int w = threadIdx.x >> 6, lane = threadIdx.x & 63;
    int r = lane & 15, q = lane >> 4;
    int i = rb * 64 + w * 16 + r;          // A-fragment row
    int cols = NN / G;
    int jbase = g * cols;
    const int nsteps = cols / 32;

    float srcv = src[i];
    float sM = srcv + DBOUND;
    float Mi = fmaxf(sM, ALPHA * sM);      // upper bound of row max
    float sL  = srcv * L2E;
    float MiL = Mi * L2E;
    float C1 = sL - MiL;
    float C2 = fmaf(sL, ALPHA, -MiL);

    f32x4 acc0{}, acc1{}, acc2{}, acc3{}, acc4{};
    short8 ones;
    #pragma unroll
    for (int k = 0; k < 8; ++k) ones[k] = (short)0x3F80;  // bf16 1.0

    const int4*   ap = (const int4*)(adj + (size_t)i * NN + jbase) + q * 2;
    const float4* dp = (const float4*)(dst2 + jbase) + q * 2;
    const short8* wp = (const short8*)(WhT + (size_t)r * NN + jbase) + q;
    const int SB = 2 * NN;                 // 16 WhT rows, in short8 units

    int4   ca0, ca1, na0, na1;
    float4 cd0, cd1, nd0, nd1;
    short8 cb0, cb1, cb2, cb3, nb0, nb1, nb2, nb3;

    // prologue: load group for t=0
    cd0 = dp[0]; cd1 = dp[1];
    ca0 = ap[0]; ca1 = ap[1];
    cb0 = wp[0]; cb1 = wp[SB]; cb2 = wp[2 * SB]; cb3 = wp[3 * SB];

#define PF(A0, A1, D0, D1, B0, B1, B2, B3, tn) \
    D0 = dp[(tn) * 8]; D1 = dp[(tn) * 8 + 1]; \
    A0 = ap[(tn) * 8]; A1 = ap[(tn) * 8 + 1]; \
    B0 = wp[(tn) * 4]; B1 = wp[(tn) * 4 + SB]; \
    B2 = wp[(tn) * 4 + 2 * SB]; B3 = wp[(tn) * 4 + 3 * SB];

#define PEL(dv, av, eo) { \
    float t1 = (dv) + C1; \
    float t2 = fmaf((dv), ALPHA, C2); \
    float e = __builtin_amdgcn_exp2f(fmaxf(t1, t2)); \
    eo = ((av) > 0) ? e : 0.0f; }

#define BODY(A0, A1, D0, D1, B0, B1, B2, B3) { \
    float e0, e1, e2, e3, e4, e5, e6, e7; \
    PEL(D0.x, A0.x, e0) PEL(D0.y, A0.y, e1) \
    PEL(D0.z, A0.z, e2) PEL(D0.w, A0.w, e3) \
    PEL(D1.x, A1.x, e4) PEL(D1.y, A1.y, e5) \
    PEL(D1.z, A1.z, e6) PEL(D1.w, A1.w, e7) \
    unsigned w0 = __builtin_amdgcn_perm(fb(e1), fb(e0), 0x07060302u); \
    unsigned w1 = __builtin_amdgcn_perm(fb(e3), fb(e2), 0x07060302u); \
    unsigned w2 = __builtin_amdgcn_perm(fb(e5), fb(e4), 0x07060302u); \
    unsigned w3 = __builtin_amdgcn_perm(fb(e7), fb(e6), 0x07060302u); \
    short8 af = __builtin_bit_cast(short8, make_uint4(w0, w1, w2, w3)); \
    acc0 = __builtin_amdgcn_mfma_f32_16x16x32_bf16(af, B0, acc0, 0, 0, 0); \
    acc1 = __builtin_amdgcn_mfma_f32_16x16x32_bf16(af, B1, acc1, 0, 0, 0); \
    acc2 = __builtin_amdgcn_mfma_f32_16x16x32_bf16(af, B2, acc2, 0, 0, 0); \
    acc3 = __builtin_amdgcn_mfma_f32_16x16x32_bf16(af, B3, acc3, 0, 0, 0); \
    acc4 = __builtin_amdgcn_mfma_f32_16x16x32_bf16(af, ones, acc4, 0, 0, 0); }

    int t = 0;
    for (;;) {
        int tn = t + 1; if (tn >= nsteps) tn = 0;
        PF(na0, na1, nd0, nd1, nb0, nb1, nb2, nb3, tn)
        BODY(ca0, ca1, cd0, cd1, cb0, cb1, cb2, cb3)
        ++t; if (t == nsteps) break;
        tn = t + 1; if (tn >= nsteps) tn = 0;
        PF(ca0, ca1, cd0, cd1, cb0, cb1, cb2, cb3, tn)
        BODY(na0, na1, nd0, nd1, nb0, nb1, nb2, nb3)
        ++t; if (t == nsteps) break;
    }
#undef PF
#undef PEL
#undef BODY

    // acc4: every column holds the row-sum; C rows = q*4 + reg.
    int ic = rb * 64 + w * 16 + q * 4;
    if (r == 0) {
        #pragma unroll
        for (int reg = 0; reg < 4; ++reg)
            lpart[(size_t)g * NN + ic + reg] = acc4[reg];
    }

    size_t ob = (size_t)g * (size_t)(NN * F);
    #pragma unroll
    for (int reg = 0; reg < 4; ++reg) {
        size_t ro = ob + (size_t)(ic + reg) * F + r;
        Opart[ro]      = acc0[reg];
        Opart[ro + 16] = acc1[reg];
        Opart[ro + 32] = acc2[reg];
        Opart[ro + 48] = acc3[reg];
    }
}

// Kernel C: out = elu( (sum_g Opart) / (sum_g lpart) )
__global__ __launch_bounds__(256) void k_reduce(const float* __restrict__ Opart,
        const float* __restrict__ lpart, float* __restrict__ out, int G) {
    int idx = blockIdx.x * 256 + threadIdx.x;
    int i = idx >> 6;
    float o = 0.f, l = 0.f;
    for (int g = 0; g < G; ++g) {
        o += Opart[(size_t)g * (NN * F) + idx];
        l += lpart[(size_t)g * NN + i];
    }
    float hp = o / l;
    out[idx] = hp > 0.f ? hp : __expf(hp) - 1.f;
}

extern "C" void kernel_launch(void* const* d_in, const int* in_sizes, int n_in,
                              void* d_out, int out_size, void* d_ws, size_t ws_size,
                              hipStream_t stream) {
    const float* h  = (const float*)d_in[0];
    const int* adj  = (const int*)d_in[1];
    const float* W  = (const float*)d_in[2];
    const float* a  = (const float*)d_in[3];
    float* out = (float*)d_out;

    char* ws = (char*)d_ws;
    const size_t OFF_WHT  = 0;                            // 1 MB bf16 WhT
    const size_t OFF_SRC  = (1u << 20);
    const size_t OFF_DST  = OFF_SRC + (32u << 10);
    const size_t OFF_LP   = OFF_DST + (32u << 10);
    const size_t OFF_OP   = OFF_LP + 8ull * NN * 4;       // lpart reserved for G<=8

    short* WhT   = (short*)(ws + OFF_WHT);
    float* src   = (float*)(ws + OFF_SRC);
    float* dst2  = (float*)(ws + OFF_DST);
    float* lpart = (float*)(ws + OFF_LP);
    float* Opart = (float*)(ws + OFF_OP);

    int G = 8;
    while (G > 1 && OFF_OP + (size_t)G * NN * F * 4 > ws_size) G >>= 1;

    k_prep<<<NN / 4, 256, 0, stream>>>(h, W, a, WhT, src, dst2);
    k_attn<<<(NN / 64) * G, 256, 0, stream>>>(adj, WhT, src, dst2, Opart, lpart, G);
    k_reduce<<<(NN * F) / 256, 256, 0, stream>>>(Opart, lpart, out, G);
}